// Round 10
// baseline (346.412 us; speedup 1.0000x reference)
//
#include <hip/hip_runtime.h>
#include <hip/hip_bf16.h>

typedef __bf16 bf16;
typedef __bf16 bf16x8 __attribute__((ext_vector_type(8)));
typedef float f32x4 __attribute__((ext_vector_type(4)));
typedef _Float16 f16;
typedef _Float16 f16x2 __attribute__((ext_vector_type(2)));

#define MFMA16(A, B, C) __builtin_amdgcn_mfma_f32_16x16x32_bf16((A), (B), (C), 0, 0, 0)

static __device__ __forceinline__ void gload16(const bf16* g, bf16* l) {
    __builtin_amdgcn_global_load_lds((const __attribute__((address_space(1))) void*)g,
                                     (__attribute__((address_space(3))) void*)l, 16, 0, 0);
}

// ---------------------------------------------------------------------------
// Fused dtype-detect + fp32->bf16 convert for x + 4 weights (verified r7/r8).
// Wave-0 ballot on Wq's first 64 bf16-halves; block 0 publishes the flag
// before the early-return. flag=1: fp32 inputs; flag=0: bf16.
// ---------------------------------------------------------------------------
__global__ __launch_bounds__(256) void convert_all(const void* x, const void* w0,
                                                   const void* w1, const void* w2,
                                                   const void* w3, bf16* xb, bf16* b0,
                                                   bf16* b1, bf16* b2, bf16* b3,
                                                   int* flagp) {
    __shared__ int sflag;
    const int t = threadIdx.x;
    if (t < 64) {
        float v = (float)((const bf16*)w0)[t];
        unsigned long long bad = __ballot(!(fabsf(v) < 1.0f));
        if (t == 0) sflag = bad ? 1 : 0;
    }
    __syncthreads();
    const int flag = sflag;
    if (blockIdx.x == 0 && t == 0) *flagp = flag;
    if (flag == 0) return;
    int id = (blockIdx.x * 256 + t) * 4;
    const int XN = 1 << 22;  // 4M
    const float* src;
    bf16* dst;
    int off;
    if (id < XN) {
        src = (const float*)x; dst = xb; off = id;
    } else {
        int r = id - XN;
        int wi = r >> 20;
        off = r & ((1 << 20) - 1);
        src = (const float*)(wi == 0 ? w0 : wi == 1 ? w1 : wi == 2 ? w2 : w3);
        dst = (wi == 0 ? b0 : wi == 1 ? b1 : wi == 2 ? b2 : b3);
    }
    float4 v = *(const float4*)(src + off);
    bf16 o[4] = {(bf16)v.x, (bf16)v.y, (bf16)v.z, (bf16)v.w};
    *(uint2*)(dst + off) = *(uint2*)o;
}

// ---------------------------------------------------------------------------
// 128x128-tile NT GEMM, 256 thr (4 waves 2x2), BK=32, double-buffered
// global_load_lds staging — r8-proven schedule + LDS RoPE table (r5) + bf16
// split-K partials (r6).
// MODE 0 (QKV, grid dim3(24,32)): RoPE epilogue Q/K, transpose V.
// MODE 1 (out-proj, grid 512): split-K 2-way, bf16 partials, 2 blocks/CU.
//   Round-10: reduce_out FUSED via threadfence-reduction idiom — after the
//   partial store: threadfence(all) -> syncthreads -> t0 atomicAdd(cnt[slot]);
//   second finisher (old==1) threadfence-acquires and reduces its 128x128
//   slot (p0+p1 -> dout, 64 els/thread). cnt zeroed by combine_kernel
//   (stream-ordered before MODE 1; kernel-boundary flushes make it visible).
// ---------------------------------------------------------------------------
template <int MODE>
__global__ __launch_bounds__(256, 3) void gemm_nt(const void* rawA, const bf16* convA,
                                                  const void* rW0, const bf16* cW0,
                                                  const void* rW1, const bf16* cW1,
                                                  const void* rW2, const bf16* cW2,
                                                  bf16* Qo, bf16* Ko, bf16* Vt,
                                                  bf16* p0, bf16* p1,
                                                  const int* flagp, int* cnt,
                                                  void* dout) {
    const int K = 1024;
    __shared__ __attribute__((aligned(16))) bf16 lsA[2][128 * 32];
    __shared__ __attribute__((aligned(16))) bf16 lsB[2][128 * 32];
    __shared__ __attribute__((aligned(8))) f16 ropeT[(MODE == 0) ? 8192 : 2];
    const int flag = *flagp;
    const bf16* A = flag ? convA : (const bf16*)rawA;
    int tensor, n0, m0, ks, slotid;
    const bf16* W;
    if (MODE == 0) {
        tensor = blockIdx.x >> 3;
        n0 = (blockIdx.x & 7) * 128;
        m0 = blockIdx.y * 128;
        ks = 0;
        slotid = 0;
        W = tensor == 0 ? (flag ? cW0 : (const bf16*)rW0)
          : tensor == 1 ? (flag ? cW1 : (const bf16*)rW1)
                        : (flag ? cW2 : (const bf16*)rW2);
    } else {
        const int bid = blockIdx.x;
        ks = bid & 1;
        slotid = bid >> 1;  // 0..255
        m0 = (slotid & 31) * 128;
        n0 = (slotid >> 5) * 128;
        tensor = 0;
        W = flag ? cW0 : (const bf16*)rW0;
    }
    const int t = threadIdx.x;
    const int w = t >> 6, lane = t & 63;
    const int wr = w >> 1, wc = w & 1;
    const int llo = lane & 15, quad = lane >> 4;
    const int sel = (llo >> 1) & 3;  // read-side chunk swizzle

    // Build per-block RoPE table (MODE 0): cos/sin for s in [m0, m0+128),
    // d2 in [0,32). Ordered before epilogue reads by the loop's barriers.
    if constexpr (MODE == 0) {
#pragma unroll
        for (int i = 0; i < 16; ++i) {
            int e = t * 16 + i;  // 0..4095
            int sloc = e >> 5, d2 = e & 31;
            int s = (m0 + sloc) & 2047;
            float freq = exp2f((float)d2 * -0.4152410118609203f);
            float rev = (float)s * freq * 0.15915494309189535f;
            rev -= floorf(rev);
            int sw = d2 ^ ((sloc & 3) << 3);
            ropeT[(sloc * 32 + sw) * 2] = (f16)__builtin_amdgcn_cosf(rev);
            ropeT[(sloc * 32 + sw) * 2 + 1] = (f16)__builtin_amdgcn_sinf(rev);
        }
    }

    f32x4 acc[4][4] = {};

    auto stage = [&](int k0, int buf) {
#pragma unroll
        for (int j = 0; j < 2; ++j) {  // A: 128 rows x 4 chunks = 512
            int c = j * 256 + t;
            int row = c >> 2, pos = c & 3;
            int g = pos ^ ((row >> 1) & 3);
            gload16(A + (size_t)(m0 + row) * K + k0 + g * 8, &lsA[buf][c * 8]);
        }
#pragma unroll
        for (int j = 0; j < 2; ++j) {  // B: 128 rows x 4 chunks
            int c = j * 256 + t;
            int row = c >> 2, pos = c & 3;
            int g = pos ^ ((row >> 1) & 3);
            gload16(W + (size_t)(n0 + row) * K + k0 + g * 8, &lsB[buf][c * 8]);
        }
    };

    auto compute = [&](int buf) {
        bf16x8 a[4], bb[4];
#pragma unroll
        for (int mi = 0; mi < 4; ++mi) {
            int r = wr * 64 + mi * 16 + llo;
            a[mi] = *(const bf16x8*)&lsA[buf][r * 32 + ((quad ^ sel) * 8)];
        }
#pragma unroll
        for (int ni = 0; ni < 4; ++ni) {
            int r = wc * 64 + ni * 16 + llo;
            bb[ni] = *(const bf16x8*)&lsB[buf][r * 32 + ((quad ^ sel) * 8)];
        }
#pragma unroll
        for (int mi = 0; mi < 4; ++mi)
#pragma unroll
            for (int ni = 0; ni < 4; ++ni)
                acc[mi][ni] = MFMA16(a[mi], bb[ni], acc[mi][ni]);
    };

    const int kbase = (MODE == 1) ? ks * 512 : 0;
    const int NIT = (MODE == 1) ? 16 : 32;

    stage(kbase, 0);
    for (int it = 0; it < NIT; it += 2) {
        __syncthreads();  // drains buf0 loads (issued one compute-phase ago)
        stage(kbase + (it + 1) * 32, 1);
        compute(0);
        __syncthreads();  // drains buf1 loads
        if (it + 2 < NIT) stage(kbase + (it + 2) * 32, 0);
        compute(1);
    }

#pragma unroll
    for (int mi = 0; mi < 4; ++mi)
#pragma unroll
        for (int ni = 0; ni < 4; ++ni)
#pragma unroll
            for (int r = 0; r < 4; ++r) {
                int row = m0 + wr * 64 + mi * 16 + quad * 4 + r;
                int col = n0 + wc * 64 + ni * 16 + llo;
                float v = acc[mi][ni][r];
                if (MODE == 1) {
                    bf16* dst = ks ? p1 : p0;
                    dst[(size_t)row * 1024 + col] = (bf16)v;
                } else if (tensor == 2) {
                    int b = row >> 11, s = row & 2047;
                    Vt[((size_t)b * 1024 + col) * 2048 + s] = (bf16)v;
                } else {
                    int d = col & 63;
                    int sloc = wr * 64 + mi * 16 + quad * 4 + r;
                    int sw = (d >> 1) ^ ((sloc & 3) << 3);
                    float partner = __shfl_xor(v, 1);
                    f16x2 cp = *(const f16x2*)&ropeT[(sloc * 32 + sw) * 2];
                    float cs = (float)cp[0];
                    float sn = (float)cp[1];
                    float outv = v * cs + partner * sn * ((d & 1) ? 1.0f : -1.0f);
                    bf16* dst = (tensor == 0) ? Qo : Ko;
                    dst[(size_t)row * 1024 + col] = (bf16)outv;
                }
            }

    // ---- Fused split-K reduction (MODE 1): last block per slot reduces. ----
    if constexpr (MODE == 1) {
        __shared__ int sdone;
        __threadfence();   // release this block's partial stores (device scope)
        __syncthreads();   // all threads' fences done before the atomic
        if (t == 0) sdone = (atomicAdd(&cnt[slotid], 1) == 1);
        __syncthreads();
        if (sdone) {
            __threadfence();  // acquire: other block's stores now visible
            const int row = m0 + (t >> 1);
            const int cb = n0 + (t & 1) * 64;
#pragma unroll
            for (int j = 0; j < 8; ++j) {
                const size_t idx = (size_t)row * 1024 + cb + j * 8;
                bf16x8 a = *(const bf16x8*)(p0 + idx);
                bf16x8 b = *(const bf16x8*)(p1 + idx);
                float s[8];
#pragma unroll
                for (int e = 0; e < 8; ++e) s[e] = (float)a[e] + (float)b[e];
                if (flag) {
                    float4 lo = {s[0], s[1], s[2], s[3]};
                    float4 hi = {s[4], s[5], s[6], s[7]};
                    *(float4*)((float*)dout + idx) = lo;
                    *(float4*)((float*)dout + idx + 4) = hi;
                } else {
                    bf16 o[8];
#pragma unroll
                    for (int e = 0; e < 8; ++e) o[e] = (bf16)s[e];
                    *(uint4*)((bf16*)dout + idx) = *(uint4*)o;
                }
            }
        }
    }
}

// ---------------------------------------------------------------------------
// Causal flash attention (r8 proven version). Split-kv two-pass; K/V staged
// to LDS via global_load_lds, double-buffered.
// Blocks 0..511: ib = 15-((blk&255)>>5) in [8,15], kv-split s = blk>>8.
// Blocks 512..767: ib = (blk-512)>>5 in [0,7], full range, direct output.
// 768 blocks = 3/CU resident; no-max softmax -> linear partial combine.
// ---------------------------------------------------------------------------
__global__ __launch_bounds__(256, 3) void attn_kernel(const bf16* __restrict__ Q,
                                                      const bf16* __restrict__ Kr,
                                                      const bf16* __restrict__ Vt,
                                                      bf16* __restrict__ O,
                                                      bf16* __restrict__ Opart,
                                                      float* __restrict__ lws) {
    __shared__ __attribute__((aligned(16))) bf16 lsK[2][64 * 64];
    __shared__ __attribute__((aligned(16))) bf16 lsV[2][64 * 64];
    __shared__ __attribute__((aligned(16))) bf16 lsP[4][32 * 64];
    const int blk = blockIdx.x;
    int ib, bh, s, tt0, tt1;
    bool split;
    if (blk < 512) {
        split = true;
        s = blk >> 8;
        int c = blk & 255;
        ib = 15 - (c >> 5);
        bh = c & 31;
        tt0 = s ? (ib + 1) : 0;
        tt1 = s ? (2 * ib + 1) : ib;
    } else {
        split = false;
        s = 0;
        int c = blk - 512;
        ib = c >> 5;
        bh = c & 31;
        tt0 = 0;
        tt1 = 2 * ib + 1;
    }
    const int b = bh >> 4, h = bh & 15;
    const int t = threadIdx.x, w = t >> 6, lane = t & 63;
    const int llo = lane & 15, quad = lane >> 4;
    const int q0w = ib * 128 + w * 32;

    bf16x8 aQ[2][2];
#pragma unroll
    for (int qi = 0; qi < 2; ++qi) {
        const size_t qb =
            ((size_t)(b * 2048 + q0w + qi * 16 + llo)) * 1024 + h * 64 + quad * 8;
        aQ[qi][0] = *(const bf16x8*)&Q[qb];
        aQ[qi][1] = *(const bf16x8*)&Q[qb + 32];
    }

    f32x4 o[2][4] = {};
    float lpart[2] = {0.f, 0.f};
    const float SC = 0.18033688011112042f;  // log2(e)/8
    const int qlane0 = q0w + llo;

    const int srow8 = lane >> 3;
    const int sc = (lane & 7) ^ srow8;

    auto stage = [&](int tt, int buf) {
        const int kv0 = tt * 64;
#pragma unroll
        for (int jj = 0; jj < 2; ++jj) {
            int seg = w + jj * 4;
            int rowk = seg * 8 + srow8;
            gload16(&Kr[((size_t)(b * 2048 + kv0 + rowk)) * 1024 + h * 64 + sc * 8],
                    &lsK[buf][seg * 512 + lane * 8]);
            gload16(&Vt[((size_t)(b * 1024 + h * 64 + rowk)) * 2048 + kv0 + sc * 8],
                    &lsV[buf][seg * 512 + lane * 8]);
        }
    };

    stage(tt0, 0);

    for (int tt = tt0; tt <= tt1; ++tt) {
        const int cur = (tt - tt0) & 1;
        const int kv0 = tt * 64;
        __syncthreads();
        if (tt + 1 <= tt1) stage(tt + 1, cur ^ 1);

        if (kv0 <= q0w + 31) {
            bf16x8 kf[4][2];
#pragma unroll
            for (int half = 0; half < 4; ++half) {
                int rk = half * 16 + llo;
                kf[half][0] = *(const bf16x8*)&lsK[cur][rk * 64 + ((quad ^ (rk & 7)) * 8)];
                kf[half][1] =
                    *(const bf16x8*)&lsK[cur][rk * 64 + (((quad + 4) ^ (rk & 7)) * 8)];
            }
            bf16x8 vf[2][4];
#pragma unroll
            for (int kc = 0; kc < 2; ++kc)
#pragma unroll
                for (int g = 0; g < 4; ++g) {
                    int rv = g * 16 + llo;
                    int cg = kc * 4 + quad;
                    vf[kc][g] =
                        *(const bf16x8*)&lsV[cur][rv * 64 + ((cg ^ (rv & 7)) * 8)];
                }

            const bool need_mask = (kv0 + 63 >= q0w);
#pragma unroll
            for (int qi = 0; qi < 2; ++qi) {
                const int q = qlane0 + qi * 16;
                const int prow = qi * 16 + llo;
#pragma unroll
                for (int half = 0; half < 4; ++half) {
                    f32x4 z = {};
                    z = MFMA16(kf[half][0], aQ[qi][0], z);  // S^T: rows kv, cols q
                    z = MFMA16(kf[half][1], aQ[qi][1], z);
                    union { bf16 hh[4]; uint2 uu; } pk;
                    if (need_mask) {
                        int kvb = kv0 + half * 16 + quad * 4;
#pragma unroll
                        for (int r = 0; r < 4; ++r) {
                            float e = (kvb + r <= q) ? z[r] * SC : -INFINITY;
                            float p = __builtin_amdgcn_exp2f(e);
                            lpart[qi] += p;
                            pk.hh[r] = (bf16)p;
                        }
                    } else {
#pragma unroll
                        for (int r = 0; r < 4; ++r) {
                            float p = __builtin_amdgcn_exp2f(z[r] * SC);
                            lpart[qi] += p;
                            pk.hh[r] = (bf16)p;
                        }
                    }
                    int cw = 2 * half + (quad >> 1);
                    *(uint2*)&lsP[w][prow * 64 + ((cw ^ (llo & 7)) * 8) + (quad & 1) * 4] =
                        pk.uu;
                }
            }
            __builtin_amdgcn_wave_barrier();  // P writes before P reads (same wave)
#pragma unroll
            for (int qi = 0; qi < 2; ++qi) {
                const int prow = qi * 16 + llo;
#pragma unroll
                for (int kc = 0; kc < 2; ++kc) {
                    int cr = 4 * kc + quad;
                    bf16x8 aP =
                        *(const bf16x8*)&lsP[w][prow * 64 + ((cr ^ (llo & 7)) * 8)];
#pragma unroll
                    for (int g = 0; g < 4; ++g) o[qi][g] = MFMA16(aP, vf[kc][g], o[qi][g]);
                }
            }
            __builtin_amdgcn_wave_barrier();
        }
    }

    float lfull[2];
#pragma unroll
    for (int qi = 0; qi < 2; ++qi) {
        float l = lpart[qi];
        l += __shfl_xor(l, 16);
        l += __shfl_xor(l, 32);
        lfull[qi] = l;
    }

    if (split) {
        const int slotw = ((ib - 8) * 32 + bh) * 2 + s;
        bf16* op = Opart + (size_t)slotw * 8192;
#pragma unroll
        for (int qi = 0; qi < 2; ++qi) {
#pragma unroll
            for (int r = 0; r < 4; ++r) {
                int row_in = w * 32 + qi * 16 + quad * 4 + r;
#pragma unroll
                for (int g = 0; g < 4; ++g)
                    op[row_in * 64 + g * 16 + llo] = (bf16)o[qi][g][r];
            }
            if (quad == 0) lws[slotw * 128 + w * 32 + qi * 16 + llo] = lfull[qi];
        }
    } else {
#pragma unroll
        for (int qi = 0; qi < 2; ++qi)
#pragma unroll
            for (int r = 0; r < 4; ++r) {
                float l = __shfl(lfull[qi], (lane & 48) | (quad * 4 + r));
                float inv = 1.f / l;
                int q = q0w + qi * 16 + quad * 4 + r;
                size_t ob = ((size_t)(b * 2048 + q)) * 1024 + h * 64;
#pragma unroll
                for (int g = 0; g < 4; ++g)
                    O[ob + g * 16 + llo] = (bf16)(o[qi][g][r] * inv);
            }
    }
}

// ---------------------------------------------------------------------------
// Combine split-kv partials for q in [1024,2048): AO = (o0+o1)/(l0+l1).
// Vectorized 4 elements/thread along d; grid 2048. Round-10: block 0 also
// zeroes the 256 split-K slot counters (stream-ordered before MODE-1 gemm;
// re-zeroed every launch for graph replay).
// ---------------------------------------------------------------------------
__global__ __launch_bounds__(256) void combine_kernel(const bf16* __restrict__ Opart,
                                                      const float* __restrict__ lws,
                                                      bf16* __restrict__ AO,
                                                      int* __restrict__ cnt) {
    if (blockIdx.x == 0) cnt[threadIdx.x] = 0;
    int vid = blockIdx.x * 256 + threadIdx.x;  // 512K total, 4 d-elems each
    int d0 = (vid & 15) * 4;
    int h = (vid >> 4) & 15;
    int qoff = (vid >> 8) & 1023;
    int b = vid >> 18;
    int ib8 = qoff >> 7;  // ib - 8
    int q_in = qoff & 127;
    int slot = (ib8 * 32 + (b * 16 + h)) * 2;
    size_t base = (size_t)slot * 8192 + q_in * 64 + d0;
    union { uint2 u; bf16 v[4]; } o0, o1, ov;
    o0.u = *(const uint2*)&Opart[base];
    o1.u = *(const uint2*)&Opart[base + 8192];
    float l = lws[slot * 128 + q_in] + lws[(slot + 1) * 128 + q_in];
    float inv = 1.f / l;
#pragma unroll
    for (int j = 0; j < 4; ++j) ov.v[j] = (bf16)(((float)o0.v[j] + (float)o1.v[j]) * inv);
    int q = 1024 + qoff;
    *(uint2*)&AO[((size_t)(b * 2048 + q)) * 1024 + h * 64 + d0] = ov.u;
}

// ---------------------------------------------------------------------------
extern "C" void kernel_launch(void* const* d_in, const int* in_sizes, int n_in,
                              void* d_out, int out_size, void* d_ws, size_t ws_size,
                              hipStream_t stream) {
    const size_t TN = (size_t)4096 * 1024;

    int* flag = (int*)d_ws;
    bf16* Q = (bf16*)((char*)d_ws + 256);
    bf16* Kb = Q + TN;
    bf16* Vt = Kb + TN;   // [B, H*dk, S] transposed; cnt overlays after attn
    bf16* xb = Vt + TN;   // bf16 x copy; then Opart; then p1
    bf16* Wb0 = xb + TN;  // weight copies; lws overlays after QKV
    bf16* Wb1 = Wb0 + TN / 4;
    bf16* Wb2 = Wb1 + TN / 4;
    bf16* Wb3 = Wb2 + TN / 4;
    bf16* AO = Q;              // attention output aliases Q
    bf16* Opart = xb;          // split-kv partial O (8MB; xb dead after QKV)
    float* lws = (float*)Wb0;  // split-kv partial l (256KB; Wb0 dead after QKV)
    bf16* p0 = Kb;             // split-K partial 0 (Kb dead after attn)
    bf16* p1 = xb;             // split-K partial 1 (Opart dead after combine)
    int* cnt = (int*)Vt;       // split-K slot counters (Vt dead after attn)

    convert_all<<<8192, 256, 0, stream>>>(d_in[0], d_in[1], d_in[2], d_in[3], d_in[4],
                                          xb, Wb0, Wb1, Wb2, Wb3, flag);

    gemm_nt<0><<<dim3(24, 32), 256, 0, stream>>>(d_in[0], xb, d_in[1], Wb0, d_in[2],
                                                 Wb1, d_in[3], Wb2, Q, Kb, Vt, nullptr,
                                                 nullptr, flag, nullptr, nullptr);

    attn_kernel<<<768, 256, 0, stream>>>(Q, Kb, Vt, AO, Opart, lws);
    combine_kernel<<<2048, 256, 0, stream>>>(Opart, lws, AO, cnt);

    gemm_nt<1><<<512, 256, 0, stream>>>(AO, AO, d_in[4], Wb3, nullptr, nullptr,
                                        nullptr, nullptr, nullptr, nullptr, nullptr,
                                        p0, p1, flag, cnt, d_out);
}

// Round 11
// 188.979 us; speedup vs baseline: 1.8331x; 1.8331x over previous
//
#include <hip/hip_runtime.h>
#include <hip/hip_bf16.h>

typedef __bf16 bf16;
typedef __bf16 bf16x8 __attribute__((ext_vector_type(8)));
typedef float f32x4 __attribute__((ext_vector_type(4)));
typedef _Float16 f16;
typedef _Float16 f16x2 __attribute__((ext_vector_type(2)));

#define MFMA16(A, B, C) __builtin_amdgcn_mfma_f32_16x16x32_bf16((A), (B), (C), 0, 0, 0)

static __device__ __forceinline__ void gload16(const bf16* g, bf16* l) {
    __builtin_amdgcn_global_load_lds((const __attribute__((address_space(1))) void*)g,
                                     (__attribute__((address_space(3))) void*)l, 16, 0, 0);
}

// ---------------------------------------------------------------------------
// Fused dtype-detect + fp32->bf16 convert for x + 4 weights (verified r7/r8).
// Wave-0 ballot on Wq's first 64 bf16-halves; block 0 publishes the flag
// before the early-return. flag=1: fp32 inputs; flag=0: bf16.
// ---------------------------------------------------------------------------
__global__ __launch_bounds__(256) void convert_all(const void* x, const void* w0,
                                                   const void* w1, const void* w2,
                                                   const void* w3, bf16* xb, bf16* b0,
                                                   bf16* b1, bf16* b2, bf16* b3,
                                                   int* flagp) {
    __shared__ int sflag;
    const int t = threadIdx.x;
    if (t < 64) {
        float v = (float)((const bf16*)w0)[t];
        unsigned long long bad = __ballot(!(fabsf(v) < 1.0f));
        if (t == 0) sflag = bad ? 1 : 0;
    }
    __syncthreads();
    const int flag = sflag;
    if (blockIdx.x == 0 && t == 0) *flagp = flag;
    if (flag == 0) return;
    int id = (blockIdx.x * 256 + t) * 4;
    const int XN = 1 << 22;  // 4M
    const float* src;
    bf16* dst;
    int off;
    if (id < XN) {
        src = (const float*)x; dst = xb; off = id;
    } else {
        int r = id - XN;
        int wi = r >> 20;
        off = r & ((1 << 20) - 1);
        src = (const float*)(wi == 0 ? w0 : wi == 1 ? w1 : wi == 2 ? w2 : w3);
        dst = (wi == 0 ? b0 : wi == 1 ? b1 : wi == 2 ? b2 : b3);
    }
    float4 v = *(const float4*)(src + off);
    bf16 o[4] = {(bf16)v.x, (bf16)v.y, (bf16)v.z, (bf16)v.w};
    *(uint2*)(dst + off) = *(uint2*)o;
}

// ---------------------------------------------------------------------------
// 128x128-tile NT GEMM, 256 thr (4 waves 2x2), BK=32, double-buffered
// global_load_lds staging — round-0 proven schedule + round-5 LDS RoPE table
// (verified: QKV 57.3 -> 53.8us) + round-6 bf16 split-K partials.
// MODE 0 (QKV, grid dim3(24,32)): RoPE epilogue Q/K, transpose V.
// MODE 1 (out-proj, grid 512): split-K 2-way, bf16 partials, 2 blocks/CU.
// NOTE (r10 lesson): do NOT fuse the split-K reduction via __threadfence —
// device-scope fences flush/invalidate the per-XCD L2 on MI355X (not
// cross-coherent); 512 blocks of fences turned a ~20us kernel into 190us.
// ---------------------------------------------------------------------------
template <int MODE>
__global__ __launch_bounds__(256, 3) void gemm_nt(const void* rawA, const bf16* convA,
                                                  const void* rW0, const bf16* cW0,
                                                  const void* rW1, const bf16* cW1,
                                                  const void* rW2, const bf16* cW2,
                                                  bf16* Qo, bf16* Ko, bf16* Vt,
                                                  bf16* p0, bf16* p1,
                                                  const int* flagp) {
    const int K = 1024;
    __shared__ __attribute__((aligned(16))) bf16 lsA[2][128 * 32];
    __shared__ __attribute__((aligned(16))) bf16 lsB[2][128 * 32];
    __shared__ __attribute__((aligned(8))) f16 ropeT[(MODE == 0) ? 8192 : 2];
    const int flag = *flagp;
    const bf16* A = flag ? convA : (const bf16*)rawA;
    int tensor, n0, m0, ks;
    const bf16* W;
    if (MODE == 0) {
        tensor = blockIdx.x >> 3;
        n0 = (blockIdx.x & 7) * 128;
        m0 = blockIdx.y * 128;
        ks = 0;
        W = tensor == 0 ? (flag ? cW0 : (const bf16*)rW0)
          : tensor == 1 ? (flag ? cW1 : (const bf16*)rW1)
                        : (flag ? cW2 : (const bf16*)rW2);
    } else {
        const int bid = blockIdx.x;
        ks = bid & 1;
        const int slot = bid >> 1;  // 0..255
        m0 = (slot & 31) * 128;
        n0 = (slot >> 5) * 128;
        tensor = 0;
        W = flag ? cW0 : (const bf16*)rW0;
    }
    const int t = threadIdx.x;
    const int w = t >> 6, lane = t & 63;
    const int wr = w >> 1, wc = w & 1;
    const int llo = lane & 15, quad = lane >> 4;
    const int sel = (llo >> 1) & 3;  // read-side chunk swizzle

    // Build per-block RoPE table (MODE 0): cos/sin for s in [m0, m0+128),
    // d2 in [0,32). 16 entries/thread; ordered before epilogue reads by the
    // main loop's __syncthreads chain.
    if constexpr (MODE == 0) {
#pragma unroll
        for (int i = 0; i < 16; ++i) {
            int e = t * 16 + i;  // 0..4095
            int sloc = e >> 5, d2 = e & 31;
            int s = (m0 + sloc) & 2047;
            float freq = exp2f((float)d2 * -0.4152410118609203f);
            float rev = (float)s * freq * 0.15915494309189535f;
            rev -= floorf(rev);
            int sw = d2 ^ ((sloc & 3) << 3);
            ropeT[(sloc * 32 + sw) * 2] = (f16)__builtin_amdgcn_cosf(rev);
            ropeT[(sloc * 32 + sw) * 2 + 1] = (f16)__builtin_amdgcn_sinf(rev);
        }
    }

    f32x4 acc[4][4] = {};

    auto stage = [&](int k0, int buf) {
#pragma unroll
        for (int j = 0; j < 2; ++j) {  // A: 128 rows x 4 chunks = 512
            int c = j * 256 + t;
            int row = c >> 2, pos = c & 3;
            int g = pos ^ ((row >> 1) & 3);
            gload16(A + (size_t)(m0 + row) * K + k0 + g * 8, &lsA[buf][c * 8]);
        }
#pragma unroll
        for (int j = 0; j < 2; ++j) {  // B: 128 rows x 4 chunks
            int c = j * 256 + t;
            int row = c >> 2, pos = c & 3;
            int g = pos ^ ((row >> 1) & 3);
            gload16(W + (size_t)(n0 + row) * K + k0 + g * 8, &lsB[buf][c * 8]);
        }
    };

    auto compute = [&](int buf) {
        bf16x8 a[4], bb[4];
#pragma unroll
        for (int mi = 0; mi < 4; ++mi) {
            int r = wr * 64 + mi * 16 + llo;
            a[mi] = *(const bf16x8*)&lsA[buf][r * 32 + ((quad ^ sel) * 8)];
        }
#pragma unroll
        for (int ni = 0; ni < 4; ++ni) {
            int r = wc * 64 + ni * 16 + llo;
            bb[ni] = *(const bf16x8*)&lsB[buf][r * 32 + ((quad ^ sel) * 8)];
        }
#pragma unroll
        for (int mi = 0; mi < 4; ++mi)
#pragma unroll
            for (int ni = 0; ni < 4; ++ni)
                acc[mi][ni] = MFMA16(a[mi], bb[ni], acc[mi][ni]);
    };

    const int kbase = (MODE == 1) ? ks * 512 : 0;
    const int NIT = (MODE == 1) ? 16 : 32;

    stage(kbase, 0);
    for (int it = 0; it < NIT; it += 2) {
        __syncthreads();  // drains buf0 loads (issued one compute-phase ago)
        stage(kbase + (it + 1) * 32, 1);
        compute(0);
        __syncthreads();  // drains buf1 loads
        if (it + 2 < NIT) stage(kbase + (it + 2) * 32, 0);
        compute(1);
    }

#pragma unroll
    for (int mi = 0; mi < 4; ++mi)
#pragma unroll
        for (int ni = 0; ni < 4; ++ni)
#pragma unroll
            for (int r = 0; r < 4; ++r) {
                int row = m0 + wr * 64 + mi * 16 + quad * 4 + r;
                int col = n0 + wc * 64 + ni * 16 + llo;
                float v = acc[mi][ni][r];
                if (MODE == 1) {
                    bf16* dst = ks ? p1 : p0;
                    dst[(size_t)row * 1024 + col] = (bf16)v;
                } else if (tensor == 2) {
                    int b = row >> 11, s = row & 2047;
                    Vt[((size_t)b * 1024 + col) * 2048 + s] = (bf16)v;
                } else {
                    int d = col & 63;
                    int sloc = wr * 64 + mi * 16 + quad * 4 + r;
                    int sw = (d >> 1) ^ ((sloc & 3) << 3);
                    float partner = __shfl_xor(v, 1);
                    f16x2 cp = *(const f16x2*)&ropeT[(sloc * 32 + sw) * 2];
                    float cs = (float)cp[0];
                    float sn = (float)cp[1];
                    float outv = v * cs + partner * sn * ((d & 1) ? 1.0f : -1.0f);
                    bf16* dst = (tensor == 0) ? Qo : Ko;
                    dst[(size_t)row * 1024 + col] = (bf16)outv;
                }
            }
}

// ---------------------------------------------------------------------------
// Sum split-K bf16 partials and cast: out = p0 + p1 (fp32 or bf16 per flag).
// 8 elements/thread, grid 2048.
// ---------------------------------------------------------------------------
__global__ __launch_bounds__(256) void reduce_out(const bf16* p0, const bf16* p1,
                                                  void* dout, const int* flagp) {
    int i = (blockIdx.x * 256 + threadIdx.x) * 8;
    bf16x8 a = *(const bf16x8*)(p0 + i);
    bf16x8 b = *(const bf16x8*)(p1 + i);
    float s[8];
#pragma unroll
    for (int j = 0; j < 8; ++j) s[j] = (float)a[j] + (float)b[j];
    if (*flagp) {
        float4 lo = {s[0], s[1], s[2], s[3]};
        float4 hi = {s[4], s[5], s[6], s[7]};
        *(float4*)((float*)dout + i) = lo;
        *(float4*)((float*)dout + i + 4) = hi;
    } else {
        bf16 o[8];
#pragma unroll
        for (int j = 0; j < 8; ++j) o[j] = (bf16)s[j];
        *(uint4*)((bf16*)dout + i) = *(uint4*)o;
    }
}

// ---------------------------------------------------------------------------
// Causal flash attention (r8 proven version). Split-kv two-pass; K/V staged
// to LDS via global_load_lds, double-buffered.
// Blocks 0..511: ib = 15-((blk&255)>>5) in [8,15], kv-split s = blk>>8.
// Blocks 512..767: ib = (blk-512)>>5 in [0,7], full range, direct output.
// 768 blocks = 3/CU resident; no-max softmax -> linear partial combine.
// ---------------------------------------------------------------------------
__global__ __launch_bounds__(256, 3) void attn_kernel(const bf16* __restrict__ Q,
                                                      const bf16* __restrict__ Kr,
                                                      const bf16* __restrict__ Vt,
                                                      bf16* __restrict__ O,
                                                      bf16* __restrict__ Opart,
                                                      float* __restrict__ lws) {
    __shared__ __attribute__((aligned(16))) bf16 lsK[2][64 * 64];
    __shared__ __attribute__((aligned(16))) bf16 lsV[2][64 * 64];
    __shared__ __attribute__((aligned(16))) bf16 lsP[4][32 * 64];
    const int blk = blockIdx.x;
    int ib, bh, s, tt0, tt1;
    bool split;
    if (blk < 512) {
        split = true;
        s = blk >> 8;
        int c = blk & 255;
        ib = 15 - (c >> 5);
        bh = c & 31;
        tt0 = s ? (ib + 1) : 0;
        tt1 = s ? (2 * ib + 1) : ib;
    } else {
        split = false;
        s = 0;
        int c = blk - 512;
        ib = c >> 5;
        bh = c & 31;
        tt0 = 0;
        tt1 = 2 * ib + 1;
    }
    const int b = bh >> 4, h = bh & 15;
    const int t = threadIdx.x, w = t >> 6, lane = t & 63;
    const int llo = lane & 15, quad = lane >> 4;
    const int q0w = ib * 128 + w * 32;

    bf16x8 aQ[2][2];
#pragma unroll
    for (int qi = 0; qi < 2; ++qi) {
        const size_t qb =
            ((size_t)(b * 2048 + q0w + qi * 16 + llo)) * 1024 + h * 64 + quad * 8;
        aQ[qi][0] = *(const bf16x8*)&Q[qb];
        aQ[qi][1] = *(const bf16x8*)&Q[qb + 32];
    }

    f32x4 o[2][4] = {};
    float lpart[2] = {0.f, 0.f};
    const float SC = 0.18033688011112042f;  // log2(e)/8
    const int qlane0 = q0w + llo;

    const int srow8 = lane >> 3;
    const int sc = (lane & 7) ^ srow8;

    auto stage = [&](int tt, int buf) {
        const int kv0 = tt * 64;
#pragma unroll
        for (int jj = 0; jj < 2; ++jj) {
            int seg = w + jj * 4;
            int rowk = seg * 8 + srow8;
            gload16(&Kr[((size_t)(b * 2048 + kv0 + rowk)) * 1024 + h * 64 + sc * 8],
                    &lsK[buf][seg * 512 + lane * 8]);
            gload16(&Vt[((size_t)(b * 1024 + h * 64 + rowk)) * 2048 + kv0 + sc * 8],
                    &lsV[buf][seg * 512 + lane * 8]);
        }
    };

    stage(tt0, 0);

    for (int tt = tt0; tt <= tt1; ++tt) {
        const int cur = (tt - tt0) & 1;
        const int kv0 = tt * 64;
        __syncthreads();
        if (tt + 1 <= tt1) stage(tt + 1, cur ^ 1);

        if (kv0 <= q0w + 31) {
            bf16x8 kf[4][2];
#pragma unroll
            for (int half = 0; half < 4; ++half) {
                int rk = half * 16 + llo;
                kf[half][0] = *(const bf16x8*)&lsK[cur][rk * 64 + ((quad ^ (rk & 7)) * 8)];
                kf[half][1] =
                    *(const bf16x8*)&lsK[cur][rk * 64 + (((quad + 4) ^ (rk & 7)) * 8)];
            }
            bf16x8 vf[2][4];
#pragma unroll
            for (int kc = 0; kc < 2; ++kc)
#pragma unroll
                for (int g = 0; g < 4; ++g) {
                    int rv = g * 16 + llo;
                    int cg = kc * 4 + quad;
                    vf[kc][g] =
                        *(const bf16x8*)&lsV[cur][rv * 64 + ((cg ^ (rv & 7)) * 8)];
                }

            const bool need_mask = (kv0 + 63 >= q0w);
#pragma unroll
            for (int qi = 0; qi < 2; ++qi) {
                const int q = qlane0 + qi * 16;
                const int prow = qi * 16 + llo;
#pragma unroll
                for (int half = 0; half < 4; ++half) {
                    f32x4 z = {};
                    z = MFMA16(kf[half][0], aQ[qi][0], z);  // S^T: rows kv, cols q
                    z = MFMA16(kf[half][1], aQ[qi][1], z);
                    union { bf16 hh[4]; uint2 uu; } pk;
                    if (need_mask) {
                        int kvb = kv0 + half * 16 + quad * 4;
#pragma unroll
                        for (int r = 0; r < 4; ++r) {
                            float e = (kvb + r <= q) ? z[r] * SC : -INFINITY;
                            float p = __builtin_amdgcn_exp2f(e);
                            lpart[qi] += p;
                            pk.hh[r] = (bf16)p;
                        }
                    } else {
#pragma unroll
                        for (int r = 0; r < 4; ++r) {
                            float p = __builtin_amdgcn_exp2f(z[r] * SC);
                            lpart[qi] += p;
                            pk.hh[r] = (bf16)p;
                        }
                    }
                    int cw = 2 * half + (quad >> 1);
                    *(uint2*)&lsP[w][prow * 64 + ((cw ^ (llo & 7)) * 8) + (quad & 1) * 4] =
                        pk.uu;
                }
            }
            __builtin_amdgcn_wave_barrier();  // P writes before P reads (same wave)
#pragma unroll
            for (int qi = 0; qi < 2; ++qi) {
                const int prow = qi * 16 + llo;
#pragma unroll
                for (int kc = 0; kc < 2; ++kc) {
                    int cr = 4 * kc + quad;
                    bf16x8 aP =
                        *(const bf16x8*)&lsP[w][prow * 64 + ((cr ^ (llo & 7)) * 8)];
#pragma unroll
                    for (int g = 0; g < 4; ++g) o[qi][g] = MFMA16(aP, vf[kc][g], o[qi][g]);
                }
            }
            __builtin_amdgcn_wave_barrier();
        }
    }

    float lfull[2];
#pragma unroll
    for (int qi = 0; qi < 2; ++qi) {
        float l = lpart[qi];
        l += __shfl_xor(l, 16);
        l += __shfl_xor(l, 32);
        lfull[qi] = l;
    }

    if (split) {
        const int slotw = ((ib - 8) * 32 + bh) * 2 + s;
        bf16* op = Opart + (size_t)slotw * 8192;
#pragma unroll
        for (int qi = 0; qi < 2; ++qi) {
#pragma unroll
            for (int r = 0; r < 4; ++r) {
                int row_in = w * 32 + qi * 16 + quad * 4 + r;
#pragma unroll
                for (int g = 0; g < 4; ++g)
                    op[row_in * 64 + g * 16 + llo] = (bf16)o[qi][g][r];
            }
            if (quad == 0) lws[slotw * 128 + w * 32 + qi * 16 + llo] = lfull[qi];
        }
    } else {
#pragma unroll
        for (int qi = 0; qi < 2; ++qi)
#pragma unroll
            for (int r = 0; r < 4; ++r) {
                float l = __shfl(lfull[qi], (lane & 48) | (quad * 4 + r));
                float inv = 1.f / l;
                int q = q0w + qi * 16 + quad * 4 + r;
                size_t ob = ((size_t)(b * 2048 + q)) * 1024 + h * 64;
#pragma unroll
                for (int g = 0; g < 4; ++g)
                    O[ob + g * 16 + llo] = (bf16)(o[qi][g][r] * inv);
            }
    }
}

// ---------------------------------------------------------------------------
// Combine split-kv partials for q in [1024,2048): AO = (o0+o1)/(l0+l1).
// Vectorized 4 elements/thread along d; grid 2048.
// ---------------------------------------------------------------------------
__global__ __launch_bounds__(256) void combine_kernel(const bf16* __restrict__ Opart,
                                                      const float* __restrict__ lws,
                                                      bf16* __restrict__ AO) {
    int vid = blockIdx.x * 256 + threadIdx.x;  // 512K total, 4 d-elems each
    int d0 = (vid & 15) * 4;
    int h = (vid >> 4) & 15;
    int qoff = (vid >> 8) & 1023;
    int b = vid >> 18;
    int ib8 = qoff >> 7;  // ib - 8
    int q_in = qoff & 127;
    int slot = (ib8 * 32 + (b * 16 + h)) * 2;
    size_t base = (size_t)slot * 8192 + q_in * 64 + d0;
    union { uint2 u; bf16 v[4]; } o0, o1, ov;
    o0.u = *(const uint2*)&Opart[base];
    o1.u = *(const uint2*)&Opart[base + 8192];
    float l = lws[slot * 128 + q_in] + lws[(slot + 1) * 128 + q_in];
    float inv = 1.f / l;
#pragma unroll
    for (int j = 0; j < 4; ++j) ov.v[j] = (bf16)(((float)o0.v[j] + (float)o1.v[j]) * inv);
    int q = 1024 + qoff;
    *(uint2*)&AO[((size_t)(b * 2048 + q)) * 1024 + h * 64 + d0] = ov.u;
}

// ---------------------------------------------------------------------------
extern "C" void kernel_launch(void* const* d_in, const int* in_sizes, int n_in,
                              void* d_out, int out_size, void* d_ws, size_t ws_size,
                              hipStream_t stream) {
    const size_t TN = (size_t)4096 * 1024;

    int* flag = (int*)d_ws;
    bf16* Q = (bf16*)((char*)d_ws + 256);
    bf16* Kb = Q + TN;
    bf16* Vt = Kb + TN;   // [B, H*dk, S] transposed
    bf16* xb = Vt + TN;   // bf16 x copy; then Opart; dead after combine
    bf16* Wb0 = xb + TN;  // weight copies; lws; dead after combine
    bf16* Wb1 = Wb0 + TN / 4;
    bf16* Wb2 = Wb1 + TN / 4;
    bf16* Wb3 = Wb2 + TN / 4;
    bf16* AO = Q;              // attention output aliases Q
    bf16* Opart = xb;          // split-kv partial O (8MB)
    float* lws = (float*)Wb0;  // split-kv partial l (256KB)
    bf16* p0 = Kb;             // split-K partial 0 (bf16, 8MB; Kb dead after attn)
    bf16* p1 = xb;             // split-K partial 1 (bf16, 8MB; xb dead after combine)

    convert_all<<<8192, 256, 0, stream>>>(d_in[0], d_in[1], d_in[2], d_in[3], d_in[4],
                                          xb, Wb0, Wb1, Wb2, Wb3, flag);

    gemm_nt<0><<<dim3(24, 32), 256, 0, stream>>>(d_in[0], xb, d_in[1], Wb0, d_in[2],
                                                 Wb1, d_in[3], Wb2, Q, Kb, Vt, nullptr,
                                                 nullptr, flag);

    attn_kernel<<<768, 256, 0, stream>>>(Q, Kb, Vt, AO, Opart, lws);
    combine_kernel<<<2048, 256, 0, stream>>>(Opart, lws, AO);

    gemm_nt<1><<<512, 256, 0, stream>>>(AO, AO, d_in[4], Wb3, nullptr, nullptr,
                                        nullptr, nullptr, nullptr, nullptr, nullptr,
                                        p0, p1, flag);
    reduce_out<<<2048, 256, 0, stream>>>(p0, p1, d_out, flag);
}